// Round 2
// baseline (2725.821 us; speedup 1.0000x reference)
//
#include <hip/hip_runtime.h>
#include <math.h>

#define DMODEL 1024
#define NHEAD 16
#define DKH 64
#define DFFN 4096
#define BATCH 2
#define SEQ 512
#define NLAYER 4
#define ROWS (BATCH*SEQ)                         // 1024
#define BH (BATCH*NHEAD)                         // 32
#define ATTN_ELEMS ((size_t)BATCH*NHEAD*SEQ*SEQ) // 8,388,608 per layer

typedef __attribute__((ext_vector_type(8))) short bf16x8;
typedef __attribute__((ext_vector_type(8))) unsigned short u16x8;
typedef __attribute__((ext_vector_type(4))) float f32x4;

__device__ inline unsigned short f2bf(float f) {
    unsigned x = __float_as_uint(f);
    unsigned r = (x + 0x7fffu + ((x >> 16) & 1u)) >> 16;
    return (unsigned short)r;
}

// ---------------------------------------------------------------------------
// transpose_cast: in [batch][K][N] fp32  ->  out [batch][N][K] bf16
// grid (N/64, K/64, batch), 256 threads. LDS 64x72 with n^((k>>3)&7)<<3 swizzle
// so column reads in phase 2 are ~2-way conflict.
// ---------------------------------------------------------------------------
__global__ __launch_bounds__(256) void transpose_cast(
    const float* __restrict__ in, unsigned short* __restrict__ out,
    int K, int N)
{
    __shared__ float T[64][72];
    const int t = threadIdx.x;
    const int n0 = blockIdx.x * 64, k0 = blockIdx.y * 64;
    const size_t bo = (size_t)blockIdx.z * (size_t)K * N;
    in += bo; out += bo;

    const int kr = t >> 4;          // 0..15
    const int nc = (t & 15) * 4;
    #pragma unroll
    for (int p = 0; p < 4; ++p) {
        int k = kr + p * 16;
        float4 v = *(const float4*)&in[(size_t)(k0 + k) * N + n0 + nc];
        int ns = nc ^ (((k >> 3) & 7) << 3);
        *(float4*)&T[k][ns] = v;
    }
    __syncthreads();
    const int dn = t >> 3;          // 0..31
    const int kc = (t & 7) * 8;
    const int sw = ((t & 7) << 3);  // (k>>3)&7 is constant = t&7 for this lane
    #pragma unroll
    for (int p = 0; p < 2; ++p) {
        int n = dn + p * 32;
        u16x8 u;
        #pragma unroll
        for (int e = 0; e < 8; ++e)
            u[e] = f2bf(T[kc + e][n ^ sw]);
        *(u16x8*)&out[(size_t)(n0 + n) * K + k0 + kc] = u;
    }
}

// ---------------------------------------------------------------------------
// gemm_mfma: C[M,N] = A[M,K](fp32) @ Bt[N,K](bf16)^T (+bias)(+relu)
// BK=64, 4 waves in 2x2, wave tile (BM/2)x(BN/2), 16x16x32 bf16 MFMA.
// LDS tiles [row][64k] bf16 (128B rows), 16B-slot XOR swizzle slot^=(row&7):
// staging writes and frag reads both at the b128 8-cycle floor.
// SPLITK>1: grid.z splits K, partial written to C + z*M*N (no bias).
// ---------------------------------------------------------------------------
template<int BM, int BN, int RELU, int SPLITK>
__global__ __launch_bounds__(256) void gemm_mfma(
    const float* __restrict__ A, const unsigned short* __restrict__ Bt,
    const float* __restrict__ bias, float* __restrict__ C,
    int M, int N, int K)
{
    constexpr int FM = BM / 32, FN = BN / 32;
    __shared__ __align__(16) unsigned short As[BM * 64];
    __shared__ __align__(16) unsigned short Bs[BN * 64];
    const int tid = threadIdx.x;
    const int lane = tid & 63, wave = tid >> 6;
    const int m0 = blockIdx.y * BM, n0 = blockIdx.x * BN;
    const int wm = (wave >> 1) * (BM / 2), wn = (wave & 1) * (BN / 2);

    int kb = 0, klen = K;
    float* Cp = C;
    if (SPLITK > 1) {
        klen = K / SPLITK;
        kb = blockIdx.z * klen;
        Cp = C + (size_t)blockIdx.z * (size_t)M * N;
    }

    f32x4 acc[FM][FN];
    #pragma unroll
    for (int i = 0; i < FM; ++i)
        #pragma unroll
        for (int j = 0; j < FN; ++j)
            acc[i][j] = (f32x4){0.f, 0.f, 0.f, 0.f};

    for (int kk = 0; kk < klen; kk += 64) {
        const int k0 = kb + kk;
        // ---- stage A (fp32->bf16) and B (bf16) into swizzled LDS ----
        #pragma unroll
        for (int p = 0; p < (BM + BN) / 64; ++p) {
            int ch = tid + p * 256;            // 32-byte chunk id
            u16x8 u0, u1;
            unsigned short* base;
            int row, q;
            if (ch < BM * 4) {
                row = ch >> 2; q = ch & 3;
                const float* ap = &A[(size_t)(m0 + row) * K + k0 + q * 16];
                float4 v0 = *(const float4*)(ap + 0);
                float4 v1 = *(const float4*)(ap + 4);
                float4 v2 = *(const float4*)(ap + 8);
                float4 v3 = *(const float4*)(ap + 12);
                u0[0]=f2bf(v0.x); u0[1]=f2bf(v0.y); u0[2]=f2bf(v0.z); u0[3]=f2bf(v0.w);
                u0[4]=f2bf(v1.x); u0[5]=f2bf(v1.y); u0[6]=f2bf(v1.z); u0[7]=f2bf(v1.w);
                u1[0]=f2bf(v2.x); u1[1]=f2bf(v2.y); u1[2]=f2bf(v2.z); u1[3]=f2bf(v2.w);
                u1[4]=f2bf(v3.x); u1[5]=f2bf(v3.y); u1[6]=f2bf(v3.z); u1[7]=f2bf(v3.w);
                base = As;
            } else {
                int c2 = ch - BM * 4;
                row = c2 >> 2; q = c2 & 3;
                const unsigned short* bp = &Bt[(size_t)(n0 + row) * K + k0 + q * 16];
                u0 = *(const u16x8*)(bp);
                u1 = *(const u16x8*)(bp + 8);
                base = Bs;
            }
            int r7 = row & 7;
            int s0 = (2 * q) ^ r7, s1 = (2 * q + 1) ^ r7;
            *(u16x8*)((char*)base + row * 128 + s0 * 16) = u0;
            *(u16x8*)((char*)base + row * 128 + s1 * 16) = u1;
        }
        __syncthreads();
        // ---- compute: 2 k-substeps of 32 ----
        #pragma unroll
        for (int ks = 0; ks < 2; ++ks) {
            bf16x8 af[FM], bfr[FN];
            #pragma unroll
            for (int i = 0; i < FM; ++i) {
                int row = wm + i * 16 + (lane & 15);
                int slot = (ks * 4 + (lane >> 4)) ^ (row & 7);
                af[i] = *(const bf16x8*)((const char*)As + row * 128 + slot * 16);
            }
            #pragma unroll
            for (int j = 0; j < FN; ++j) {
                int row = wn + j * 16 + (lane & 15);
                int slot = (ks * 4 + (lane >> 4)) ^ (row & 7);
                bfr[j] = *(const bf16x8*)((const char*)Bs + row * 128 + slot * 16);
            }
            #pragma unroll
            for (int i = 0; i < FM; ++i)
                #pragma unroll
                for (int j = 0; j < FN; ++j)
                    acc[i][j] = __builtin_amdgcn_mfma_f32_16x16x32_bf16(
                        af[i], bfr[j], acc[i][j], 0, 0, 0);
        }
        __syncthreads();
    }

    // ---- epilogue: C/D layout col=lane&15, row=(lane>>4)*4+r (m89-verified)
    const int cl = lane & 15, rg = lane >> 4;
    #pragma unroll
    for (int j = 0; j < FN; ++j) {
        int col = n0 + wn + j * 16 + cl;
        float bv = 0.0f;
        if (SPLITK == 1) bv = bias[col];
        #pragma unroll
        for (int i = 0; i < FM; ++i) {
            int rb = m0 + wm + i * 16 + rg * 4;
            #pragma unroll
            for (int r = 0; r < 4; ++r) {
                float v = acc[i][j][r] + bv;
                if (RELU) v = fmaxf(v, 0.f);
                Cp[(size_t)(rb + r) * N + col] = v;
            }
        }
    }
}

// combine2: C = part0 + part1 + bias  (all [M,N], N=1024 here)
__global__ __launch_bounds__(256) void combine2(
    const float* __restrict__ parts, const float* __restrict__ bias,
    float* __restrict__ C, int N, int total4)
{
    int i = blockIdx.x * 256 + threadIdx.x;
    if (i >= total4) return;
    const float4* p0 = (const float4*)parts;
    const float4* p1 = (const float4*)(parts + (size_t)total4 * 4);
    float4 a = p0[i], b = p1[i];
    int col = (i * 4) & (N - 1);
    float4 bv = *(const float4*)&bias[col];
    float4 o;
    o.x = a.x + b.x + bv.x; o.y = a.y + b.y + bv.y;
    o.z = a.z + b.z + bv.z; o.w = a.w + b.w + bv.w;
    ((float4*)C)[i] = o;
}

// ---------------------------------------------------------------------------
// Fallback fp32 GEMM (round-0) — used only if ws_size too small for bf16 path
// ---------------------------------------------------------------------------
template<int RELU>
__global__ __launch_bounds__(256) void gemm_bias(
    const float* __restrict__ A, const float* __restrict__ W,
    const float* __restrict__ bias, float* __restrict__ C,
    int M, int N, int K)
{
    __shared__ float As[32][68];
    __shared__ float Ws[32][68];
    const int tid = threadIdx.x;
    const int tx = tid & 15, ty = tid >> 4;
    const int m0 = blockIdx.y * 64, n0 = blockIdx.x * 64;
    const int ac4 = tid & 7,  ar = tid >> 3;
    const int wc4 = tid & 15, wr = tid >> 4;
    float acc[4][4] = {};
    for (int k0 = 0; k0 < K; k0 += 32) {
        #pragma unroll
        for (int p = 0; p < 2; ++p) {
            int row = ar + p * 32;
            float4 av = *(const float4*)&A[(size_t)(m0 + row) * K + k0 + ac4 * 4];
            As[ac4*4+0][row] = av.x; As[ac4*4+1][row] = av.y;
            As[ac4*4+2][row] = av.z; As[ac4*4+3][row] = av.w;
        }
        #pragma unroll
        for (int p = 0; p < 2; ++p) {
            int row = wr + p * 16;
            *(float4*)&Ws[row][wc4*4] =
                *(const float4*)&W[(size_t)(k0 + row) * N + n0 + wc4 * 4];
        }
        __syncthreads();
        #pragma unroll
        for (int kk = 0; kk < 32; ++kk) {
            float4 a4 = *(const float4*)&As[kk][ty * 4];
            float4 w4 = *(const float4*)&Ws[kk][tx * 4];
            float a_[4] = {a4.x, a4.y, a4.z, a4.w};
            float w_[4] = {w4.x, w4.y, w4.z, w4.w};
            #pragma unroll
            for (int i = 0; i < 4; ++i)
                #pragma unroll
                for (int j = 0; j < 4; ++j)
                    acc[i][j] = fmaf(a_[i], w_[j], acc[i][j]);
        }
        __syncthreads();
    }
    float4 bv = *(const float4*)&bias[n0 + tx * 4];
    #pragma unroll
    for (int i = 0; i < 4; ++i) {
        float4 o;
        o.x = acc[i][0] + bv.x; o.y = acc[i][1] + bv.y;
        o.z = acc[i][2] + bv.z; o.w = acc[i][3] + bv.w;
        if (RELU) {
            o.x = fmaxf(o.x, 0.f); o.y = fmaxf(o.y, 0.f);
            o.z = fmaxf(o.z, 0.f); o.w = fmaxf(o.w, 0.f);
        }
        *(float4*)&C[(size_t)(m0 + ty * 4 + i) * N + n0 + tx * 4] = o;
    }
}

// ---------------------------------------------------------------------------
// attn_scores: out[b,h,q,k] = (Q[q,:].K[k,:]) * inv_scale ; ld-strided inputs
// ---------------------------------------------------------------------------
__global__ __launch_bounds__(256) void attn_scores(
    const float* __restrict__ Q, const float* __restrict__ Kt,
    float* __restrict__ out, float inv_scale, int ldq, int ldk)
{
    __shared__ float Qs[64][68];
    __shared__ float Ks[64][68];
    const int tid = threadIdx.x;
    const int tx = tid & 15, ty = tid >> 4;
    const int k0 = blockIdx.x * 64, q0 = blockIdx.y * 64;
    const int z = blockIdx.z;
    const int b = z >> 4, h = z & 15;

    const float* Qb = Q + (size_t)b * SEQ * ldq + h * DKH;
    const float* Kb = Kt + (size_t)b * SEQ * ldk + h * DKH;

    const int c4 = tid & 15, r = tid >> 4;
    #pragma unroll
    for (int p = 0; p < 4; ++p) {
        int row = r + p * 16;
        float4 qv = *(const float4*)&Qb[(size_t)(q0 + row) * ldq + c4 * 4];
        Qs[c4*4+0][row] = qv.x; Qs[c4*4+1][row] = qv.y;
        Qs[c4*4+2][row] = qv.z; Qs[c4*4+3][row] = qv.w;
        float4 kv = *(const float4*)&Kb[(size_t)(k0 + row) * ldk + c4 * 4];
        Ks[c4*4+0][row] = kv.x; Ks[c4*4+1][row] = kv.y;
        Ks[c4*4+2][row] = kv.z; Ks[c4*4+3][row] = kv.w;
    }
    __syncthreads();

    float acc[4][4] = {};
    #pragma unroll
    for (int kk = 0; kk < 64; ++kk) {
        float4 q4 = *(const float4*)&Qs[kk][ty * 4];
        float4 k4 = *(const float4*)&Ks[kk][tx * 4];
        float a_[4] = {q4.x, q4.y, q4.z, q4.w};
        float w_[4] = {k4.x, k4.y, k4.z, k4.w};
        #pragma unroll
        for (int i = 0; i < 4; ++i)
            #pragma unroll
            for (int j = 0; j < 4; ++j)
                acc[i][j] = fmaf(a_[i], w_[j], acc[i][j]);
    }

    float* ob = out + (size_t)z * SEQ * SEQ;
    #pragma unroll
    for (int i = 0; i < 4; ++i) {
        float4 o;
        o.x = acc[i][0] * inv_scale; o.y = acc[i][1] * inv_scale;
        o.z = acc[i][2] * inv_scale; o.w = acc[i][3] * inv_scale;
        *(float4*)&ob[(size_t)(q0 + ty * 4 + i) * SEQ + k0 + tx * 4] = o;
    }
}

// softmax_mask: in-place masked softmax, one wave per row of 512
__global__ __launch_bounds__(256) void softmax_mask(
    float* __restrict__ P, const int* __restrict__ mask, int mb, int mq)
{
    const int lane = threadIdx.x & 63;
    const int wv = threadIdx.x >> 6;
    const int row = blockIdx.x * 4 + wv;
    const int b = row >> 13;
    const int q = row & (SEQ - 1);
    float* p = P + (size_t)row * SEQ;
    const int* mrow = mask + (size_t)b * mb + (size_t)q * mq;

    float s[8];
    #pragma unroll
    for (int j = 0; j < 8; ++j) {
        float v = p[lane + j * 64];
        int m = mrow[lane + j * 64];
        s[j] = m ? v : -1e9f;
    }
    float mx = s[0];
    #pragma unroll
    for (int j = 1; j < 8; ++j) mx = fmaxf(mx, s[j]);
    #pragma unroll
    for (int o = 32; o > 0; o >>= 1) mx = fmaxf(mx, __shfl_xor(mx, o, 64));
    float e[8], sum = 0.f;
    #pragma unroll
    for (int j = 0; j < 8; ++j) { e[j] = expf(s[j] - mx); sum += e[j]; }
    #pragma unroll
    for (int o = 32; o > 0; o >>= 1) sum += __shfl_xor(sum, o, 64);
    float inv = 1.0f / sum;
    #pragma unroll
    for (int j = 0; j < 8; ++j) p[lane + j * 64] = e[j] * inv;
}

// attn_pv: ctx[b,q,h*64+d] = sum_k P[b,h,q,k] V[b,k,h*64+d]; V ld-strided
__global__ __launch_bounds__(256) void attn_pv(
    const float* __restrict__ P, const float* __restrict__ V,
    float* __restrict__ ctx, int ldv)
{
    __shared__ float Ps[32][68];
    __shared__ float Vs[32][68];
    const int tid = threadIdx.x;
    const int tx = tid & 15, ty = tid >> 4;
    const int q0 = blockIdx.x * 64;
    const int z = blockIdx.y;
    const int b = z >> 4, h = z & 15;

    const float* Pb = P + (size_t)z * SEQ * SEQ;
    const float* Vb = V + (size_t)b * SEQ * ldv + h * DKH;

    const int pc4 = tid & 7,  pr = tid >> 3;
    const int vc4 = tid & 15, vr = tid >> 4;

    float acc[4][4] = {};
    for (int k0 = 0; k0 < SEQ; k0 += 32) {
        #pragma unroll
        for (int p = 0; p < 2; ++p) {
            int row = pr + p * 32;
            float4 pv = *(const float4*)&Pb[(size_t)(q0 + row) * SEQ + k0 + pc4 * 4];
            Ps[pc4*4+0][row] = pv.x; Ps[pc4*4+1][row] = pv.y;
            Ps[pc4*4+2][row] = pv.z; Ps[pc4*4+3][row] = pv.w;
        }
        #pragma unroll
        for (int p = 0; p < 2; ++p) {
            int row = vr + p * 16;
            *(float4*)&Vs[row][vc4*4] =
                *(const float4*)&Vb[(size_t)(k0 + row) * ldv + vc4 * 4];
        }
        __syncthreads();
        #pragma unroll
        for (int kk = 0; kk < 32; ++kk) {
            float4 p4 = *(const float4*)&Ps[kk][ty * 4];
            float4 v4 = *(const float4*)&Vs[kk][tx * 4];
            float a_[4] = {p4.x, p4.y, p4.z, p4.w};
            float w_[4] = {v4.x, v4.y, v4.z, v4.w};
            #pragma unroll
            for (int i = 0; i < 4; ++i)
                #pragma unroll
                for (int j = 0; j < 4; ++j)
                    acc[i][j] = fmaf(a_[i], w_[j], acc[i][j]);
        }
        __syncthreads();
    }
    #pragma unroll
    for (int i = 0; i < 4; ++i) {
        float4 o;
        o.x = acc[i][0]; o.y = acc[i][1]; o.z = acc[i][2]; o.w = acc[i][3];
        *(float4*)&ctx[(size_t)b * SEQ * DMODEL +
                       (size_t)(q0 + ty * 4 + i) * DMODEL + h * DKH + tx * 4] = o;
    }
}

// ln_kernel: out = g*(v-mean)*rsqrt(var+eps)+b, v = x (+a); one block per row
__global__ __launch_bounds__(256) void ln_kernel(
    const float* __restrict__ x, const float* __restrict__ a,
    const float* __restrict__ g, const float* __restrict__ bt,
    float* __restrict__ outp)
{
    const int row = blockIdx.x;
    const int t = threadIdx.x;
    float4 v = *(const float4*)&x[(size_t)row * DMODEL + t * 4];
    if (a) {
        float4 av = *(const float4*)&a[(size_t)row * DMODEL + t * 4];
        v.x += av.x; v.y += av.y; v.z += av.z; v.w += av.w;
    }
    float s  = v.x + v.y + v.z + v.w;
    float sq = v.x*v.x + v.y*v.y + v.z*v.z + v.w*v.w;
    #pragma unroll
    for (int o = 32; o > 0; o >>= 1) {
        s  += __shfl_xor(s,  o, 64);
        sq += __shfl_xor(sq, o, 64);
    }
    __shared__ float rs[4], rq[4];
    const int lane = t & 63, wv = t >> 6;
    if (lane == 0) { rs[wv] = s; rq[wv] = sq; }
    __syncthreads();
    s  = rs[0] + rs[1] + rs[2] + rs[3];
    sq = rq[0] + rq[1] + rq[2] + rq[3];
    const float mean = s * (1.0f / DMODEL);
    const float var  = sq * (1.0f / DMODEL) - mean * mean;
    const float rstd = rsqrtf(var + 1e-5f);
    float4 gv = *(const float4*)&g[t * 4];
    float4 bv = *(const float4*)&bt[t * 4];
    float4 o;
    o.x = gv.x * (v.x - mean) * rstd + bv.x;
    o.y = gv.y * (v.y - mean) * rstd + bv.y;
    o.z = gv.z * (v.z - mean) * rstd + bv.z;
    o.w = gv.w * (v.w - mean) * rstd + bv.w;
    *(float4*)&outp[(size_t)row * DMODEL + t * 4] = o;
}

// ---------------------------------------------------------------------------
extern "C" void kernel_launch(void* const* d_in, const int* in_sizes, int n_in,
                              void* d_out, int out_size, void* d_ws, size_t ws_size,
                              hipStream_t stream)
{
    const float* src   = (const float*)d_in[0];
    const float* tgt   = (const float*)d_in[1];
    const float* encW  = (const float*)d_in[2];
    const float* encb  = (const float*)d_in[3];
    const float* encW1 = (const float*)d_in[4];
    const float* encb1 = (const float*)d_in[5];
    const float* encW2 = (const float*)d_in[6];
    const float* encb2 = (const float*)d_in[7];
    const float* encg  = (const float*)d_in[8];
    const float* enclb = (const float*)d_in[9];
    const float* encfg = (const float*)d_in[10];
    const float* encfb = (const float*)d_in[11];
    const float* dsW   = (const float*)d_in[12];
    const float* dsb   = (const float*)d_in[13];
    const float* dcW   = (const float*)d_in[14];
    const float* dcb   = (const float*)d_in[15];
    const float* dW1   = (const float*)d_in[16];
    const float* db1   = (const float*)d_in[17];
    const float* dW2   = (const float*)d_in[18];
    const float* db2   = (const float*)d_in[19];
    const float* dg    = (const float*)d_in[20];
    const float* dlb   = (const float*)d_in[21];
    const float* dfg   = (const float*)d_in[22];
    const float* dfb   = (const float*)d_in[23];
    const int* src_mask = (const int*)d_in[24];
    const int* tgt_mask = (const int*)d_in[25];

    float* out = (float*)d_out;
    float* dec_out    = out;
    float* enc_attn   = out + (size_t)ROWS * DMODEL;
    float* self_attn  = enc_attn + NLAYER * ATTN_ELEMS;
    float* cross_attn = self_attn + NLAYER * ATTN_ELEMS;

    const size_t XE = (size_t)ROWS * DMODEL;       // 1,048,576
    const size_t DD = (size_t)DMODEL * DMODEL;
    const size_t DF1 = (size_t)DMODEL * DFFN;
    const size_t WG = (size_t)16 * 1024 * 1024;    // elems per weight group

    float* ws = (float*)d_ws;
    float* x_enc   = ws;
    float* enc_out = ws + XE;
    float* x_dec   = ws + 2 * XE;
    float* qkv     = ws + 3 * XE;   // 3 XE ([1024][3072] fused, or q/k/v)
    float* ctx     = ws + 6 * XE;
    float* aout    = ws + 7 * XE;
    float* ffh     = ws + 8 * XE;   // 4 XE
    float* part    = ws + 12 * XE;  // 2 XE split-K partials
    unsigned short* wt = (unsigned short*)(ws + 14 * XE);
    unsigned short* encWt = wt;
    unsigned short* dsWt  = wt + 1 * WG;
    unsigned short* dcWt  = wt + 2 * WG;
    unsigned short* eW1t  = wt + 3 * WG;
    unsigned short* eW2t  = wt + 4 * WG;
    unsigned short* dW1t  = wt + 5 * WG;
    unsigned short* dW2t  = wt + 6 * WG;

    const size_t need = 14 * XE * sizeof(float) + 7 * WG * sizeof(unsigned short);
    const bool use_mfma = (ws_size >= need);
    const int T4 = (int)(XE / 4);   // 262144 float4s in a 1024x1024 matrix

    if (use_mfma) {
        // ---- pre-transpose+cast all weights to bf16 [N][K] ----
        transpose_cast<<<dim3(16, 16, 16), 256, 0, stream>>>(encW, encWt, DMODEL, DMODEL);
        transpose_cast<<<dim3(16, 16, 16), 256, 0, stream>>>(dsW,  dsWt,  DMODEL, DMODEL);
        transpose_cast<<<dim3(16, 16, 16), 256, 0, stream>>>(dcW,  dcWt,  DMODEL, DMODEL);
        transpose_cast<<<dim3(64, 16, 4),  256, 0, stream>>>(encW1, eW1t, DMODEL, DFFN);
        transpose_cast<<<dim3(16, 64, 4),  256, 0, stream>>>(encW2, eW2t, DFFN, DMODEL);
        transpose_cast<<<dim3(64, 16, 4),  256, 0, stream>>>(dW1,   dW1t, DMODEL, DFFN);
        transpose_cast<<<dim3(16, 64, 4),  256, 0, stream>>>(dW2,   dW2t, DFFN, DMODEL);
    }

    // helpers -----------------------------------------------------------
    auto gemm_f32 = [&](const float* A, const float* W, const float* b,
                        float* C, int M, int N, int K, int relu) {
        dim3 grid(N / 64, M / 64);
        if (relu) gemm_bias<1><<<grid, 256, 0, stream>>>(A, W, b, C, M, N, K);
        else      gemm_bias<0><<<grid, 256, 0, stream>>>(A, W, b, C, M, N, K);
    };
    // split-K=2 bf16 GEMM for N=1024 outputs (full-machine grid), + combine
    auto gemm_1024 = [&](const float* A, const unsigned short* Bt,
                         const float* b, float* C, int K) {
        gemm_mfma<64, 64, 0, 2><<<dim3(16, 16, 2), 256, 0, stream>>>(
            A, Bt, nullptr, part, ROWS, DMODEL, K);
        combine2<<<(T4 + 255) / 256, 256, 0, stream>>>(part, b, C, DMODEL, T4);
    };

    // one attention instance --------------------------------------------
    auto attention = [&](const float* xq, const float* xkv, bool fused_qkv,
                         const unsigned short* Wt4, const float* W4f,
                         const float* b4, float* attn_slot,
                         const int* mask, int mb, int mq) {
        const float *Qp, *Kp, *Vp; int ldq, ldk;
        if (use_mfma) {
            if (fused_qkv) {
                gemm_mfma<64, 128, 0, 1><<<dim3(24, 16), 256, 0, stream>>>(
                    xq, Wt4, b4, qkv, ROWS, 3 * DMODEL, DMODEL);
                Qp = qkv; Kp = qkv + DMODEL; Vp = qkv + 2 * DMODEL;
                ldq = ldk = 3 * DMODEL;
            } else {
                gemm_1024(xq, Wt4, b4, qkv, DMODEL);               // Q
                gemm_mfma<64, 64, 0, 1><<<dim3(32, 16), 256, 0, stream>>>(
                    xkv, Wt4 + DD, b4 + DMODEL, qkv + XE, ROWS, 2 * DMODEL, DMODEL);
                Qp = qkv; Kp = qkv + XE; Vp = qkv + XE + DMODEL;
                ldq = DMODEL; ldk = 2 * DMODEL;
            }
        } else {
            gemm_f32(xq,  W4f + 0 * DD, b4 + 0 * DMODEL, qkv,          ROWS, DMODEL, DMODEL, 0);
            gemm_f32(xkv, W4f + 1 * DD, b4 + 1 * DMODEL, qkv + XE,     ROWS, DMODEL, DMODEL, 0);
            gemm_f32(xkv, W4f + 2 * DD, b4 + 2 * DMODEL, qkv + 2 * XE, ROWS, DMODEL, DMODEL, 0);
            Qp = qkv; Kp = qkv + XE; Vp = qkv + 2 * XE;
            ldq = ldk = DMODEL;
        }
        attn_scores<<<dim3(8, 8, BH), 256, 0, stream>>>(Qp, Kp, attn_slot, 0.125f, ldq, ldk);
        softmax_mask<<<BH * SEQ / 4, 256, 0, stream>>>(attn_slot, mask, mb, mq);
        attn_pv<<<dim3(8, BH), 256, 0, stream>>>(attn_slot, Vp, ctx, ldk);
        if (use_mfma) gemm_1024(ctx, Wt4 + 3 * DD, b4 + 3 * DMODEL, aout, DMODEL);
        else gemm_f32(ctx, W4f + 3 * DD, b4 + 3 * DMODEL, aout, ROWS, DMODEL, DMODEL, 0);
    };

    auto ffn = [&](const float* x, const unsigned short* W1t, const float* W1f,
                   const float* b1, const unsigned short* W2t, const float* W2f,
                   const float* b2) {
        if (use_mfma) {
            gemm_mfma<64, 128, 1, 1><<<dim3(32, 16), 256, 0, stream>>>(
                x, W1t, b1, ffh, ROWS, DFFN, DMODEL);
            gemm_mfma<64, 64, 0, 2><<<dim3(16, 16, 2), 256, 0, stream>>>(
                ffh, W2t, nullptr, part, ROWS, DMODEL, DFFN);
            combine2<<<(T4 + 255) / 256, 256, 0, stream>>>(part, b2, aout, DMODEL, T4);
        } else {
            gemm_f32(x, W1f, b1, ffh, ROWS, DFFN, DMODEL, 1);
            gemm_f32(ffh, W2f, b2, aout, ROWS, DMODEL, DFFN, 0);
        }
    };

    // ---------------- encoder ----------------
    const float* xin = src;
    for (int l = 0; l < NLAYER; ++l) {
        attention(xin, xin, true,
                  encWt + (size_t)l * 4 * DD, encW + (size_t)l * 4 * DD,
                  encb + (size_t)l * 4 * DMODEL,
                  enc_attn + (size_t)l * ATTN_ELEMS, src_mask, SEQ, 0);
        ln_kernel<<<ROWS, 256, 0, stream>>>(xin, aout,
            encg + (size_t)(l * 2 + 0) * DMODEL, enclb + (size_t)(l * 2 + 0) * DMODEL, x_enc);
        ffn(x_enc, eW1t + (size_t)l * DF1, encW1 + (size_t)l * DF1, encb1 + (size_t)l * DFFN,
            eW2t + (size_t)l * DF1, encW2 + (size_t)l * DF1, encb2 + (size_t)l * DMODEL);
        ln_kernel<<<ROWS, 256, 0, stream>>>(x_enc, aout,
            encg + (size_t)(l * 2 + 1) * DMODEL, enclb + (size_t)(l * 2 + 1) * DMODEL, x_enc);
        xin = x_enc;
    }
    ln_kernel<<<ROWS, 256, 0, stream>>>(x_enc, nullptr, encfg, encfb, enc_out);

    // ---------------- decoder ----------------
    const float* xdin = tgt;
    for (int l = 0; l < NLAYER; ++l) {
        attention(xdin, xdin, true,
                  dsWt + (size_t)l * 4 * DD, dsW + (size_t)l * 4 * DD,
                  dsb + (size_t)l * 4 * DMODEL,
                  self_attn + (size_t)l * ATTN_ELEMS, tgt_mask, SEQ * SEQ, SEQ);
        ln_kernel<<<ROWS, 256, 0, stream>>>(xdin, aout,
            dg + (size_t)(l * 3 + 0) * DMODEL, dlb + (size_t)(l * 3 + 0) * DMODEL, x_dec);
        attention(x_dec, enc_out, false,
                  dcWt + (size_t)l * 4 * DD, dcW + (size_t)l * 4 * DD,
                  dcb + (size_t)l * 4 * DMODEL,
                  cross_attn + (size_t)l * ATTN_ELEMS, src_mask, SEQ, 0);
        ln_kernel<<<ROWS, 256, 0, stream>>>(x_dec, aout,
            dg + (size_t)(l * 3 + 1) * DMODEL, dlb + (size_t)(l * 3 + 1) * DMODEL, x_dec);
        ffn(x_dec, dW1t + (size_t)l * DF1, dW1 + (size_t)l * DF1, db1 + (size_t)l * DFFN,
            dW2t + (size_t)l * DF1, dW2 + (size_t)l * DF1, db2 + (size_t)l * DMODEL);
        ln_kernel<<<ROWS, 256, 0, stream>>>(x_dec, aout,
            dg + (size_t)(l * 3 + 2) * DMODEL, dlb + (size_t)(l * 3 + 2) * DMODEL, x_dec);
        xdin = x_dec;
    }
    ln_kernel<<<ROWS, 256, 0, stream>>>(x_dec, nullptr, dfg, dfb, dec_out);

    (void)in_sizes; (void)n_in; (void)out_size;
}